// Round 5
// baseline (1065.995 us; speedup 1.0000x reference)
//
#include <hip/hip_runtime.h>

#define HH 384
#define WW 384
#define HWSZ (HH * WW)
#define NIMG 24

__device__ __forceinline__ int refl(int i, int n) {
    if (i < 0) i = -i;
    if (i >= n) i = 2 * n - 2 - i;
    return i;
}

// 5-tap Gaussian (sigma=1, normalized), double-precision constants cast to float
__device__ const float LPW[5] = {
    0.054488684549642945f, 0.24420134200323332f, 0.40261994689424746f,
    0.24420134200323332f, 0.054488684549642945f
};

// ===================== compile-time filter generation =======================
// constexpr fp64 math (range-reduced Taylor / Newton); error ~1e-16 rel,
// invisible after the final cast to fp32.
constexpr double CPI = 3.141592653589793;  // == numpy.pi as double

constexpr double cexp(double x) {
    int k = 0; double t = x;
    while (t > 0.25 || t < -0.25) { t *= 0.5; ++k; }
    double sum = 1.0, term = 1.0;
    for (int n = 1; n <= 14; ++n) { term *= t / n; sum += term; }
    for (int i = 0; i < k; ++i) sum *= sum;
    return sum;
}
constexpr double ccos(double x) {   // x in [0, pi)
    double sgn = 1.0;
    if (x > CPI * 0.5) { x = CPI - x; sgn = -1.0; }
    double x2 = x * x, sum = 1.0, term = 1.0;
    for (int n = 1; n <= 12; ++n) { term *= -x2 / ((2.0 * n - 1) * (2.0 * n)); sum += term; }
    return sgn * sum;
}
constexpr double csin(double x) {   // x in [0, pi)
    if (x > CPI * 0.5) x = CPI - x;
    double x2 = x * x, sum = x, term = x;
    for (int n = 1; n <= 12; ++n) { term *= -x2 / ((2.0 * n) * (2.0 * n + 1)); sum += term; }
    return sum;
}
constexpr double csqrt(double x) {
    if (x <= 0.0) return 0.0;
    double y = x > 1.0 ? x : 1.0;
    for (int i = 0; i < 80; ++i) y = 0.5 * (y + x / y);
    return y;
}

struct F225 { double v[225]; };

constexpr F225 make_filter(int s, int d, int nd) {
    double angle = CPI * (double)d / (double)nd;
    double scale = (double)(s + 1);
    double sx = 2.0 * scale, sy = 0.5 * scale;
    double ca = ccos(angle), sa = csin(angle);
    F225 f{};
    double sum = 0.0;
    for (int r = 0; r < 15; ++r)
        for (int c = 0; c < 15; ++c) {
            double X = (double)(c - 7), Y = (double)(r - 7);
            double Xr = X * ca - Y * sa;
            double Yr = X * sa + Y * ca;
            double k = cexp(-0.5 * (Xr * Xr / (sx * sx) + Yr * Yr / (sy * sy))) * Xr / (sx * sx);
            f.v[r * 15 + c] = k; sum += k;
        }
    double mean = sum / 225.0;
    double ss = 0.0;
    for (int i = 0; i < 225; ++i) { f.v[i] -= mean; ss += f.v[i] * f.v[i]; }
    double n = csqrt(ss);
    if (n > 1e-6) for (int i = 0; i < 225; ++i) f.v[i] /= n;
    return f;
}

// one constexpr evaluation per filter (keeps each under the step limit)
template <int S, int D>
struct Filt { static constexpr F225 v = make_filter(S, D, S == 0 ? 4 : (S == 1 ? 8 : 16)); };

constexpr const F225& getF(int s, int d) {
    if (s == 0) {
        if (d == 0) return Filt<0, 0>::v;
        if (d == 1) return Filt<0, 1>::v;
        return Filt<0, 2>::v;
    } else if (s == 1) {
        if (d == 0) return Filt<1, 0>::v;
        if (d == 1) return Filt<1, 1>::v;
        if (d == 2) return Filt<1, 2>::v;
        if (d == 3) return Filt<1, 3>::v;
        return Filt<1, 4>::v;
    } else {
        if (d == 0) return Filt<2, 0>::v;
        if (d == 1) return Filt<2, 1>::v;
        if (d == 2) return Filt<2, 2>::v;
        if (d == 3) return Filt<2, 3>::v;
        if (d == 4) return Filt<2, 4>::v;
        if (d == 5) return Filt<2, 5>::v;
        if (d == 6) return Filt<2, 6>::v;
        if (d == 7) return Filt<2, 7>::v;
        return Filt<2, 8>::v;
    }
}

// Packed mirror-pair tables (same algebra as the verified round-3 kernel):
// point-antisymmetry G(-u,-v) = -G(u,v); x-mirror G_{nd-d}(u,v) = G_d(u,-v).
// out_d = P + Q, out_{nd-d} = P - Q;
//   A(j,k) = (G_dP(u,v)+G_dP(u,-v))/2, dP = (k==0 ? NH : k)
//   B(j,k) = (G_dQ(u,v)-G_dQ(u,-v))/2, dQ = (k==0 ? 0  : k)
// positions j: 0..6 (0,v) [A==0], 7..13 (u,0) [B==0], 14..62 (u,v) u,v>=1.
template <int NH> struct PTab { float a[63 * NH]; float b[63 * NH]; };

template <int NH>
constexpr PTab<NH> make_ptab(int s) {
    PTab<NH> t{};
    for (int j = 0; j < 63; ++j) {
        int u, v;
        if (j < 7)       { u = 0;     v = j + 1; }
        else if (j < 14) { u = j - 6; v = 0;     }
        else { int p = j - 14; u = p / 7 + 1; v = p % 7 + 1; }
        for (int k = 0; k < NH; ++k) {
            int dP = (k == 0) ? NH : k;
            int dQ = (k == 0) ? 0 : k;
            const F225& FP = getF(s, dP);
            const F225& FQ = getF(s, dQ);
            double A = 0.5 * (FP.v[(7 + u) * 15 + (7 + v)] + FP.v[(7 + u) * 15 + (7 - v)]);
            double B = 0.5 * (FQ.v[(7 + u) * 15 + (7 + v)] - FQ.v[(7 + u) * 15 + (7 - v)]);
            t.a[j * NH + k] = (float)A;
            t.b[j * NH + k] = (float)B;
        }
    }
    return t;
}
template <int S, int NH>
struct PTbl { static constexpr PTab<NH> t = make_ptab<NH>(S); };

// ================= fused 3-stage Gaussian pyramid (one kernel) =============
// Per 32x32 tile: stage 44x44 input (halo 6, reflect), then chain
// h0->lp0(40x40)->h1->lp1(36x36)->h2->lp2(32x32) in LDS.
// Reflect-coherence: Gaussian is symmetric, so lp(refl(r)) == refl(lp)(r);
// a single reflect at the input indexing makes the whole chain exact.
__global__ __launch_bounds__(256, 4) void lp_fused(
    const float* __restrict__ in, float* __restrict__ lp0g,
    float* __restrict__ lp1g, float* __restrict__ outall) {
    __shared__ float sIN[44][48];
    __shared__ float sA[44][40];
    __shared__ float sB[40][40];

    int n = blockIdx.z;
    int bx = blockIdx.x * 32, by = blockIdx.y * 32;
    int tid = threadIdx.y * 32 + threadIdx.x;
    int yy = threadIdx.y, xx = threadIdx.x;
    const float* ip = in + (long)n * HWSZ;

    // 1: stage input 44x44 (row0 = abs by-6, col0 = abs bx-6)
    for (int l = tid; l < 44 * 44; l += 256) {
        int r = l / 44, c = l % 44;
        sIN[r][c] = ip[(long)refl(by + r - 6, HH) * WW + refl(bx + c - 6, WW)];
    }
    __syncthreads();
    // 2: h0[44][40] (col0 = abs bx-4)
    for (int l = tid; l < 44 * 40; l += 256) {
        int r = l / 40, c = l % 40;
        float s = 0.f;
#pragma unroll
        for (int i = 0; i < 5; ++i) s = fmaf(LPW[i], sIN[r][c + i], s);
        sA[r][c] = s;
    }
    __syncthreads();
    // 3: lp0[40][40] (row0 = abs by-4)
    for (int l = tid; l < 40 * 40; l += 256) {
        int r = l / 40, c = l % 40;
        float s = 0.f;
#pragma unroll
        for (int i = 0; i < 5; ++i) s = fmaf(LPW[i], sA[r + i][c], s);
        sB[r][c] = s;
    }
    __syncthreads();
    // 4: write lp0 center; 5: h1[40][36] into sIN storage (col0 = abs bx-2)
    {
        float* l0 = lp0g + (long)n * HWSZ;
#pragma unroll
        for (int rr = 0; rr < 4; ++rr)
            l0[(long)(by + yy + rr * 8) * WW + bx + xx] = sB[yy + rr * 8 + 4][xx + 4];
        float* h1 = &sIN[0][0];  // [40][36] flat
        for (int l = tid; l < 40 * 36; l += 256) {
            int r = l / 36, c = l % 36;
            float s = 0.f;
#pragma unroll
            for (int i = 0; i < 5; ++i) s = fmaf(LPW[i], sB[r][c + i], s);
            h1[r * 36 + c] = s;
        }
    }
    __syncthreads();
    // 6: lp1[36][36] into sB (row0 = abs by-2)
    {
        const float* h1 = &sIN[0][0];
        for (int l = tid; l < 36 * 36; l += 256) {
            int r = l / 36, c = l % 36;
            float s = 0.f;
#pragma unroll
            for (int i = 0; i < 5; ++i) s = fmaf(LPW[i], h1[(r + i) * 36 + c], s);
            sB[r][c] = s;
        }
    }
    __syncthreads();
    // 7: write lp1 center; 8: h2[36][32] into sA storage (col0 = abs bx)
    {
        float* l1 = lp1g + (long)n * HWSZ;
#pragma unroll
        for (int rr = 0; rr < 4; ++rr)
            l1[(long)(by + yy + rr * 8) * WW + bx + xx] = sB[yy + rr * 8 + 2][xx + 2];
        float* h2 = &sA[0][0];  // [36][32] flat
        for (int l = tid; l < 36 * 32; l += 256) {
            int r = l / 32, c = l % 32;
            float s = 0.f;
#pragma unroll
            for (int i = 0; i < 5; ++i) s = fmaf(LPW[i], sB[r][c + i], s);
            h2[r * 32 + c] = s;
        }
    }
    __syncthreads();
    // 9: lp2 -> out channel 28 (row0 of h2 = abs by-2)
    {
        const float* h2 = &sA[0][0];
#pragma unroll
        for (int rr = 0; rr < 4; ++rr) {
            int r = yy + rr * 8;
            float s = 0.f;
#pragma unroll
            for (int i = 0; i < 5; ++i) s = fmaf(LPW[i], h2[(r + i) * 32 + xx], s);
            outall[((long)n * 29 + 28) * HWSZ + (long)(by + r) * WW + bx + xx] = s;
        }
    }
}

// ---------------- directional 15x15 bank, reflect pad ----------------------
// Round-3 scalar structure, but ALL coefficients are compile-time literals
// (constexpr tables, fully unrolled) -> zero s_loads, no lgkm mixing.
template <int SIDX, int NH, int R>
__global__ __launch_bounds__(256, 4) void dir_kernel(
    const float* __restrict__ A, long as,
    const float* __restrict__ B, long bs,
    float* __restrict__ out, int c0) {
    constexpr int TH = 8 * R;            // tile height
    __shared__ float sm[TH + 14][48];

    int n = blockIdx.z;
    int tx = threadIdx.x, ty = threadIdx.y;
    int bx = blockIdx.x * 32, by = blockIdx.y * TH;

    const float* Ab = A + (long)n * as;
    const float* Bb = B + (long)n * bs;

    int lid = ty * 32 + tx;
    for (int l = lid; l < (TH + 14) * 46; l += 256) {
        int ly = l / 46, lx = l % 46;
        int gy = refl(by + ly - 7, HH);
        int gx = refl(bx + lx - 7, WW);
        long gi = (long)gy * WW + gx;
        sm[ly][lx] = Ab[gi] - Bb[gi];
    }
    __syncthreads();

    float accP[NH][R], accQ[NH][R];
#pragma unroll
    for (int k = 0; k < NH; ++k)
#pragma unroll
        for (int r = 0; r < R; ++r) { accP[k][r] = 0.f; accQ[k][r] = 0.f; }

    int xc = tx + 7;

    // H0: u=0, v=1..7 (j=v-1): A==0, only Q gets fed
#pragma unroll
    for (int v = 1; v <= 7; ++v) {
        float dv[R];
#pragma unroll
        for (int r = 0; r < R; ++r) {
            int yb = ty + 7 + 8 * r;
            dv[r] = sm[yb][xc + v] - sm[yb][xc - v];
        }
#pragma unroll
        for (int k = 0; k < NH; ++k) {
            float ca = PTbl<SIDX, NH>::t.b[(v - 1) * NH + k];   // literal
#pragma unroll
            for (int r = 0; r < R; ++r)
                accQ[k][r] = fmaf(ca, dv[r], accQ[k][r]);
        }
    }

    // u = 1..7, fully unrolled (coefs are immediates, no load pressure)
#pragma unroll
    for (int u = 1; u <= 7; ++u) {
        // Hc: v=0 (j=6+u): B==0, only P
        {
            float dvc[R];
#pragma unroll
            for (int r = 0; r < R; ++r) {
                int yb = ty + 7 + 8 * r;
                dvc[r] = sm[yb + u][xc] - sm[yb - u][xc];
            }
#pragma unroll
            for (int k = 0; k < NH; ++k) {
                float cs = PTbl<SIDX, NH>::t.a[(6 + u) * NH + k];
#pragma unroll
                for (int r = 0; r < R; ++r)
                    accP[k][r] = fmaf(cs, dvc[r], accP[k][r]);
            }
        }
        // Hp: v=1..7 (j=14+(u-1)*7+(v-1)): S->P, D->Q
#pragma unroll
        for (int v = 1; v <= 7; ++v) {
            float S[R], D[R];
#pragma unroll
            for (int r = 0; r < R; ++r) {
                int yb = ty + 7 + 8 * r;
                float a = sm[yb + u][xc + v];
                float b = sm[yb + u][xc - v];
                float c = sm[yb - u][xc + v];
                float d = sm[yb - u][xc - v];
                float t1 = a - d, t2 = b - c;
                S[r] = t1 + t2;
                D[r] = t1 - t2;
            }
            int jp = 14 + (u - 1) * 7 + (v - 1);
#pragma unroll
            for (int k = 0; k < NH; ++k) {
                float cs = PTbl<SIDX, NH>::t.a[jp * NH + k];
                float ca = PTbl<SIDX, NH>::t.b[jp * NH + k];
#pragma unroll
                for (int r = 0; r < R; ++r) {
                    accP[k][r] = fmaf(cs, S[r], accP[k][r]);
                    accQ[k][r] = fmaf(ca, D[r], accQ[k][r]);
                }
            }
        }
    }

    // outputs: d=0 -> Q[0]; d=NH -> P[0]; pair k: d=k -> P+Q, d=2NH-k -> P-Q
    long ob = ((long)n * 29 + c0) * HWSZ;
#pragma unroll
    for (int r = 0; r < R; ++r) {
        long idx = ob + (long)(by + ty + r * 8) * WW + bx + tx;
        out[idx] = accQ[0][r];
        out[idx + (long)NH * HWSZ] = accP[0][r];
#pragma unroll
        for (int k = 1; k < NH; ++k) {
            out[idx + (long)k * HWSZ] = accP[k][r] + accQ[k][r];
            out[idx + (long)(2 * NH - k) * HWSZ] = accP[k][r] - accQ[k][r];
        }
    }
}

extern "C" void kernel_launch(void* const* d_in, const int* in_sizes, int n_in,
                              void* d_out, int out_size, void* d_ws, size_t ws_size,
                              hipStream_t stream) {
    const float* x = (const float*)d_in[0];
    float* out = (float*)d_out;
    float* ws = (float*)d_ws;

    float* lp0 = ws;                        // 24 * HWSZ
    float* lp1 = lp0 + (long)NIMG * HWSZ;   // 24 * HWSZ

    dim3 blk(32, 8);
    // fused pyramid: lp0, lp1 -> ws; lp2 -> out channel 28
    lp_fused<<<dim3(12, 12, NIMG), blk, 0, stream>>>(x, lp0, lp1, out);

    // band0 = x - lp0      -> channels 0..3   (NH=2, R=4: 32x32 tiles)
    dir_kernel<0, 2, 4><<<dim3(12, 12, NIMG), blk, 0, stream>>>(
        x, HWSZ, lp0, HWSZ, out, 0);
    // band1 = lp0 - lp1    -> channels 4..11  (NH=4, R=4: 32x32 tiles)
    dir_kernel<1, 4, 4><<<dim3(12, 12, NIMG), blk, 0, stream>>>(
        lp0, HWSZ, lp1, HWSZ, out, 4);
    // band2 = lp1 - lp2    -> channels 12..27 (NH=8, R=2: 32x16 tiles)
    dir_kernel<2, 8, 2><<<dim3(12, 24, NIMG), blk, 0, stream>>>(
        lp1, HWSZ, out + 28l * HWSZ, 29l * HWSZ, out, 12);
}

// Round 6
// 604.998 us; speedup vs baseline: 1.7620x; 1.7620x over previous
//
#include <hip/hip_runtime.h>

#define HH 384
#define WW 384
#define HWSZ (HH * WW)
#define NIMG 24

__device__ __forceinline__ int refl(int i, int n) {
    if (i < 0) i = -i;
    if (i >= n) i = 2 * n - 2 - i;
    return i;
}

// 5-tap Gaussian (sigma=1, normalized), double-precision constants cast to float
__device__ const float LPW[5] = {
    0.054488684549642945f, 0.24420134200323332f, 0.40261994689424746f,
    0.24420134200323332f, 0.054488684549642945f
};

// ===================== compile-time filter generation =======================
// constexpr fp64 math (range-reduced Taylor / Newton); error ~1e-16 rel,
// invisible after the final cast to fp32. Numerically validated in round 5
// (passed, absmax identical to runtime fp64 generation).
constexpr double CPI = 3.141592653589793;  // == numpy.pi as double

constexpr double cexp(double x) {
    int k = 0; double t = x;
    while (t > 0.25 || t < -0.25) { t *= 0.5; ++k; }
    double sum = 1.0, term = 1.0;
    for (int n = 1; n <= 14; ++n) { term *= t / n; sum += term; }
    for (int i = 0; i < k; ++i) sum *= sum;
    return sum;
}
constexpr double ccos(double x) {   // x in [0, pi)
    double sgn = 1.0;
    if (x > CPI * 0.5) { x = CPI - x; sgn = -1.0; }
    double x2 = x * x, sum = 1.0, term = 1.0;
    for (int n = 1; n <= 12; ++n) { term *= -x2 / ((2.0 * n - 1) * (2.0 * n)); sum += term; }
    return sgn * sum;
}
constexpr double csin(double x) {   // x in [0, pi)
    if (x > CPI * 0.5) x = CPI - x;
    double x2 = x * x, sum = x, term = x;
    for (int n = 1; n <= 12; ++n) { term *= -x2 / ((2.0 * n) * (2.0 * n + 1)); sum += term; }
    return sum;
}
constexpr double csqrt(double x) {
    if (x <= 0.0) return 0.0;
    double y = x > 1.0 ? x : 1.0;
    for (int i = 0; i < 80; ++i) y = 0.5 * (y + x / y);
    return y;
}

struct F225 { double v[225]; };

constexpr F225 make_filter(int s, int d, int nd) {
    double angle = CPI * (double)d / (double)nd;
    double scale = (double)(s + 1);
    double sx = 2.0 * scale, sy = 0.5 * scale;
    double ca = ccos(angle), sa = csin(angle);
    F225 f{};
    double sum = 0.0;
    for (int r = 0; r < 15; ++r)
        for (int c = 0; c < 15; ++c) {
            double X = (double)(c - 7), Y = (double)(r - 7);
            double Xr = X * ca - Y * sa;
            double Yr = X * sa + Y * ca;
            double k = cexp(-0.5 * (Xr * Xr / (sx * sx) + Yr * Yr / (sy * sy))) * Xr / (sx * sx);
            f.v[r * 15 + c] = k; sum += k;
        }
    double mean = sum / 225.0;
    double ss = 0.0;
    for (int i = 0; i < 225; ++i) { f.v[i] -= mean; ss += f.v[i] * f.v[i]; }
    double n = csqrt(ss);
    if (n > 1e-6) for (int i = 0; i < 225; ++i) f.v[i] /= n;
    return f;
}

template <int S, int D>
struct Filt { static constexpr F225 v = make_filter(S, D, S == 0 ? 4 : (S == 1 ? 8 : 16)); };

constexpr const F225& getF(int s, int d) {
    if (s == 0) {
        if (d == 0) return Filt<0, 0>::v;
        if (d == 1) return Filt<0, 1>::v;
        return Filt<0, 2>::v;
    } else if (s == 1) {
        if (d == 0) return Filt<1, 0>::v;
        if (d == 1) return Filt<1, 1>::v;
        if (d == 2) return Filt<1, 2>::v;
        if (d == 3) return Filt<1, 3>::v;
        return Filt<1, 4>::v;
    } else {
        if (d == 0) return Filt<2, 0>::v;
        if (d == 1) return Filt<2, 1>::v;
        if (d == 2) return Filt<2, 2>::v;
        if (d == 3) return Filt<2, 3>::v;
        if (d == 4) return Filt<2, 4>::v;
        if (d == 5) return Filt<2, 5>::v;
        if (d == 6) return Filt<2, 6>::v;
        if (d == 7) return Filt<2, 7>::v;
        return Filt<2, 8>::v;
    }
}

// Packed mirror-pair tables (algebra verified in rounds 3-5):
// point-antisymmetry G(-u,-v) = -G(u,v); x-mirror G_{nd-d}(u,v) = G_d(u,-v).
// out_d = P + Q, out_{nd-d} = P - Q;
//   A(j,k) = (G_dP(u,v)+G_dP(u,-v))/2, dP = (k==0 ? NH : k)
//   B(j,k) = (G_dQ(u,v)-G_dQ(u,-v))/2, dQ = (k==0 ? 0  : k)
// positions j: 0..6 (0,v) [A==0], 7..13 (u,0) [B==0], 14..62 (u,v) u,v>=1.
template <int NH> struct PTab { float a[63 * NH]; float b[63 * NH]; };

template <int NH>
constexpr PTab<NH> make_ptab(int s) {
    PTab<NH> t{};
    for (int j = 0; j < 63; ++j) {
        int u, v;
        if (j < 7)       { u = 0;     v = j + 1; }
        else if (j < 14) { u = j - 6; v = 0;     }
        else { int p = j - 14; u = p / 7 + 1; v = p % 7 + 1; }
        for (int k = 0; k < NH; ++k) {
            int dP = (k == 0) ? NH : k;
            int dQ = (k == 0) ? 0 : k;
            const F225& FP = getF(s, dP);
            const F225& FQ = getF(s, dQ);
            double A = 0.5 * (FP.v[(7 + u) * 15 + (7 + v)] + FP.v[(7 + u) * 15 + (7 - v)]);
            double B = 0.5 * (FQ.v[(7 + u) * 15 + (7 + v)] - FQ.v[(7 + u) * 15 + (7 - v)]);
            t.a[j * NH + k] = (float)A;
            t.b[j * NH + k] = (float)B;
        }
    }
    return t;
}
template <int S, int NH>
struct PTbl { static constexpr PTab<NH> t = make_ptab<NH>(S); };

// ================= fused 3-stage Gaussian pyramid (one kernel) =============
// Verified correct in round 5. Per 32x32 tile: stage 44x44 (halo 6, reflect),
// chain h0->lp0(40x40)->h1->lp1(36x36)->h2->lp2(32x32) in LDS.
__global__ __launch_bounds__(256, 4) void lp_fused(
    const float* __restrict__ in, float* __restrict__ lp0g,
    float* __restrict__ lp1g, float* __restrict__ outall) {
    __shared__ float sIN[44][48];
    __shared__ float sA[44][40];
    __shared__ float sB[40][40];

    int n = blockIdx.z;
    int bx = blockIdx.x * 32, by = blockIdx.y * 32;
    int tid = threadIdx.y * 32 + threadIdx.x;
    int yy = threadIdx.y, xx = threadIdx.x;
    const float* ip = in + (long)n * HWSZ;

    for (int l = tid; l < 44 * 44; l += 256) {
        int r = l / 44, c = l % 44;
        sIN[r][c] = ip[(long)refl(by + r - 6, HH) * WW + refl(bx + c - 6, WW)];
    }
    __syncthreads();
    for (int l = tid; l < 44 * 40; l += 256) {
        int r = l / 40, c = l % 40;
        float s = 0.f;
#pragma unroll
        for (int i = 0; i < 5; ++i) s = fmaf(LPW[i], sIN[r][c + i], s);
        sA[r][c] = s;
    }
    __syncthreads();
    for (int l = tid; l < 40 * 40; l += 256) {
        int r = l / 40, c = l % 40;
        float s = 0.f;
#pragma unroll
        for (int i = 0; i < 5; ++i) s = fmaf(LPW[i], sA[r + i][c], s);
        sB[r][c] = s;
    }
    __syncthreads();
    {
        float* l0 = lp0g + (long)n * HWSZ;
#pragma unroll
        for (int rr = 0; rr < 4; ++rr)
            l0[(long)(by + yy + rr * 8) * WW + bx + xx] = sB[yy + rr * 8 + 4][xx + 4];
        float* h1 = &sIN[0][0];  // [40][36] flat
        for (int l = tid; l < 40 * 36; l += 256) {
            int r = l / 36, c = l % 36;
            float s = 0.f;
#pragma unroll
            for (int i = 0; i < 5; ++i) s = fmaf(LPW[i], sB[r][c + i], s);
            h1[r * 36 + c] = s;
        }
    }
    __syncthreads();
    {
        const float* h1 = &sIN[0][0];
        for (int l = tid; l < 36 * 36; l += 256) {
            int r = l / 36, c = l % 36;
            float s = 0.f;
#pragma unroll
            for (int i = 0; i < 5; ++i) s = fmaf(LPW[i], h1[(r + i) * 36 + c], s);
            sB[r][c] = s;
        }
    }
    __syncthreads();
    {
        float* l1 = lp1g + (long)n * HWSZ;
#pragma unroll
        for (int rr = 0; rr < 4; ++rr)
            l1[(long)(by + yy + rr * 8) * WW + bx + xx] = sB[yy + rr * 8 + 2][xx + 2];
        float* h2 = &sA[0][0];  // [36][32] flat
        for (int l = tid; l < 36 * 32; l += 256) {
            int r = l / 32, c = l % 32;
            float s = 0.f;
#pragma unroll
            for (int i = 0; i < 5; ++i) s = fmaf(LPW[i], sB[r][c + i], s);
            h2[r * 32 + c] = s;
        }
    }
    __syncthreads();
    {
        const float* h2 = &sA[0][0];
#pragma unroll
        for (int rr = 0; rr < 4; ++rr) {
            int r = yy + rr * 8;
            float s = 0.f;
#pragma unroll
            for (int i = 0; i < 5; ++i) s = fmaf(LPW[i], h2[(r + i) * 32 + xx], s);
            outall[((long)n * 29 + 28) * HWSZ + (long)(by + r) * WW + bx + xx] = s;
        }
    }
}

// ============== directional bank: per-u template step =======================
// Compile-time U => every coefficient index is a constant => folds to an
// inline fp32 literal (zero coefficient loads). The empty memory-clobber asm
// between steps fences LDS-read hoisting, bounding the scheduling window to
// one u-step (~300 insts) — same discipline as round-3's `#pragma unroll 1`
// loop, whose removal caused round-5's spill catastrophe (FETCH 55->405MB).
template <int SIDX, int NH, int R, int U>
struct UStep {
    static __device__ __forceinline__ void run(
        const float (&sm)[8 * R + 14][48], int ty, int xc,
        float (&accP)[NH][R], float (&accQ)[NH][R]) {
        // Hc: v=0 (j=6+U): B==0, P only
        {
            float dvc[R];
#pragma unroll
            for (int r = 0; r < R; ++r) {
                int yb = ty + 7 + 8 * r;
                dvc[r] = sm[yb + U][xc] - sm[yb - U][xc];
            }
#pragma unroll
            for (int k = 0; k < NH; ++k) {
                const float cs = PTbl<SIDX, NH>::t.a[(6 + U) * NH + k];  // literal
#pragma unroll
                for (int r = 0; r < R; ++r)
                    accP[k][r] = fmaf(cs, dvc[r], accP[k][r]);
            }
        }
        // Hp: v=1..7 (j=14+(U-1)*7+(v-1)): S->P, D->Q
#pragma unroll
        for (int v = 1; v <= 7; ++v) {
            float S[R], D[R];
#pragma unroll
            for (int r = 0; r < R; ++r) {
                int yb = ty + 7 + 8 * r;
                float a = sm[yb + U][xc + v];
                float b = sm[yb + U][xc - v];
                float c = sm[yb - U][xc + v];
                float d = sm[yb - U][xc - v];
                float t1 = a - d, t2 = b - c;
                S[r] = t1 + t2;
                D[r] = t1 - t2;
            }
#pragma unroll
            for (int k = 0; k < NH; ++k) {
                const float cs = PTbl<SIDX, NH>::t.a[(14 + (U - 1) * 7 + (v - 1)) * NH + k];
                const float ca = PTbl<SIDX, NH>::t.b[(14 + (U - 1) * 7 + (v - 1)) * NH + k];
#pragma unroll
                for (int r = 0; r < R; ++r) {
                    accP[k][r] = fmaf(cs, S[r], accP[k][r]);
                    accQ[k][r] = fmaf(ca, D[r], accQ[k][r]);
                }
            }
        }
        asm volatile("" ::: "memory");  // scheduling fence between u-steps
        UStep<SIDX, NH, R, U + 1>::run(sm, ty, xc, accP, accQ);
    }
};
template <int SIDX, int NH, int R>
struct UStep<SIDX, NH, R, 8> {
    static __device__ __forceinline__ void run(
        const float (&)[8 * R + 14][48], int, int,
        float (&)[NH][R], float (&)[NH][R]) {}
};

// ---------------- directional 15x15 bank, reflect pad ----------------------
template <int SIDX, int NH, int R>
__global__ __launch_bounds__(256, 4) void dir_kernel(
    const float* __restrict__ A, long as,
    const float* __restrict__ B, long bs,
    float* __restrict__ out, int c0) {
    constexpr int TH = 8 * R;            // tile height
    __shared__ float sm[TH + 14][48];

    int n = blockIdx.z;
    int tx = threadIdx.x, ty = threadIdx.y;
    int bx = blockIdx.x * 32, by = blockIdx.y * TH;

    const float* Ab = A + (long)n * as;
    const float* Bb = B + (long)n * bs;

    int lid = ty * 32 + tx;
    for (int l = lid; l < (TH + 14) * 46; l += 256) {
        int ly = l / 46, lx = l % 46;
        int gy = refl(by + ly - 7, HH);
        int gx = refl(bx + lx - 7, WW);
        long gi = (long)gy * WW + gx;
        sm[ly][lx] = Ab[gi] - Bb[gi];
    }
    __syncthreads();

    float accP[NH][R], accQ[NH][R];
#pragma unroll
    for (int k = 0; k < NH; ++k)
#pragma unroll
        for (int r = 0; r < R; ++r) { accP[k][r] = 0.f; accQ[k][r] = 0.f; }

    int xc = tx + 7;

    // H0: u=0, v=1..7 (j=v-1): A==0, Q only
#pragma unroll
    for (int v = 1; v <= 7; ++v) {
        float dv[R];
#pragma unroll
        for (int r = 0; r < R; ++r) {
            int yb = ty + 7 + 8 * r;
            dv[r] = sm[yb][xc + v] - sm[yb][xc - v];
        }
#pragma unroll
        for (int k = 0; k < NH; ++k) {
            const float ca = PTbl<SIDX, NH>::t.b[(v - 1) * NH + k];  // literal
#pragma unroll
            for (int r = 0; r < R; ++r)
                accQ[k][r] = fmaf(ca, dv[r], accQ[k][r]);
        }
    }
    asm volatile("" ::: "memory");

    // u = 1..7 as template recursion (compile-time coefs, fenced windows)
    UStep<SIDX, NH, R, 1>::run(sm, ty, xc, accP, accQ);

    // outputs: d=0 -> Q[0]; d=NH -> P[0]; pair k: d=k -> P+Q, d=2NH-k -> P-Q
    long ob = ((long)n * 29 + c0) * HWSZ;
#pragma unroll
    for (int r = 0; r < R; ++r) {
        long idx = ob + (long)(by + ty + r * 8) * WW + bx + tx;
        out[idx] = accQ[0][r];
        out[idx + (long)NH * HWSZ] = accP[0][r];
#pragma unroll
        for (int k = 1; k < NH; ++k) {
            out[idx + (long)k * HWSZ] = accP[k][r] + accQ[k][r];
            out[idx + (long)(2 * NH - k) * HWSZ] = accP[k][r] - accQ[k][r];
        }
    }
}

extern "C" void kernel_launch(void* const* d_in, const int* in_sizes, int n_in,
                              void* d_out, int out_size, void* d_ws, size_t ws_size,
                              hipStream_t stream) {
    const float* x = (const float*)d_in[0];
    float* out = (float*)d_out;
    float* ws = (float*)d_ws;

    float* lp0 = ws;                        // 24 * HWSZ
    float* lp1 = lp0 + (long)NIMG * HWSZ;   // 24 * HWSZ

    dim3 blk(32, 8);
    // fused pyramid: lp0, lp1 -> ws; lp2 -> out channel 28
    lp_fused<<<dim3(12, 12, NIMG), blk, 0, stream>>>(x, lp0, lp1, out);

    // band0 = x - lp0      -> channels 0..3   (NH=2, R=4: 32x32 tiles)
    dir_kernel<0, 2, 4><<<dim3(12, 12, NIMG), blk, 0, stream>>>(
        x, HWSZ, lp0, HWSZ, out, 0);
    // band1 = lp0 - lp1    -> channels 4..11  (NH=4, R=4: 32x32 tiles)
    dir_kernel<1, 4, 4><<<dim3(12, 12, NIMG), blk, 0, stream>>>(
        lp0, HWSZ, lp1, HWSZ, out, 4);
    // band2 = lp1 - lp2    -> channels 12..27 (NH=8, R=2: 32x16 tiles)
    dir_kernel<2, 8, 2><<<dim3(12, 24, NIMG), blk, 0, stream>>>(
        lp1, HWSZ, out + 28l * HWSZ, 29l * HWSZ, out, 12);
}

// Round 7
// 594.186 us; speedup vs baseline: 1.7940x; 1.0182x over previous
//
#include <hip/hip_runtime.h>

#define HH 384
#define WW 384
#define HWSZ (HH * WW)
#define NIMG 24

__device__ __forceinline__ int refl(int i, int n) {
    if (i < 0) i = -i;
    if (i >= n) i = 2 * n - 2 - i;
    return i;
}

// 5-tap Gaussian (sigma=1, normalized) as constexpr -> inline literals
constexpr float LPW[5] = {
    0.054488684549642945f, 0.24420134200323332f, 0.40261994689424746f,
    0.24420134200323332f, 0.054488684549642945f
};

// ===================== compile-time filter generation =======================
// constexpr fp64 math (range-reduced Taylor / Newton); error ~1e-16 rel.
// Numerically validated in rounds 5/6 (absmax identical to runtime fp64 gen).
constexpr double CPI = 3.141592653589793;  // == numpy.pi as double

constexpr double cexp(double x) {
    int k = 0; double t = x;
    while (t > 0.25 || t < -0.25) { t *= 0.5; ++k; }
    double sum = 1.0, term = 1.0;
    for (int n = 1; n <= 14; ++n) { term *= t / n; sum += term; }
    for (int i = 0; i < k; ++i) sum *= sum;
    return sum;
}
constexpr double ccos(double x) {   // x in [0, pi)
    double sgn = 1.0;
    if (x > CPI * 0.5) { x = CPI - x; sgn = -1.0; }
    double x2 = x * x, sum = 1.0, term = 1.0;
    for (int n = 1; n <= 12; ++n) { term *= -x2 / ((2.0 * n - 1) * (2.0 * n)); sum += term; }
    return sgn * sum;
}
constexpr double csin(double x) {   // x in [0, pi)
    if (x > CPI * 0.5) x = CPI - x;
    double x2 = x * x, sum = x, term = x;
    for (int n = 1; n <= 12; ++n) { term *= -x2 / ((2.0 * n) * (2.0 * n + 1)); sum += term; }
    return sum;
}
constexpr double csqrt(double x) {
    if (x <= 0.0) return 0.0;
    double y = x > 1.0 ? x : 1.0;
    for (int i = 0; i < 80; ++i) y = 0.5 * (y + x / y);
    return y;
}

struct F225 { double v[225]; };

constexpr F225 make_filter(int s, int d, int nd) {
    double angle = CPI * (double)d / (double)nd;
    double scale = (double)(s + 1);
    double sx = 2.0 * scale, sy = 0.5 * scale;
    double ca = ccos(angle), sa = csin(angle);
    F225 f{};
    double sum = 0.0;
    for (int r = 0; r < 15; ++r)
        for (int c = 0; c < 15; ++c) {
            double X = (double)(c - 7), Y = (double)(r - 7);
            double Xr = X * ca - Y * sa;
            double Yr = X * sa + Y * ca;
            double k = cexp(-0.5 * (Xr * Xr / (sx * sx) + Yr * Yr / (sy * sy))) * Xr / (sx * sx);
            f.v[r * 15 + c] = k; sum += k;
        }
    double mean = sum / 225.0;
    double ss = 0.0;
    for (int i = 0; i < 225; ++i) { f.v[i] -= mean; ss += f.v[i] * f.v[i]; }
    double n = csqrt(ss);
    if (n > 1e-6) for (int i = 0; i < 225; ++i) f.v[i] /= n;
    return f;
}

template <int S, int D>
struct Filt { static constexpr F225 v = make_filter(S, D, S == 0 ? 4 : (S == 1 ? 8 : 16)); };

constexpr const F225& getF(int s, int d) {
    if (s == 0) {
        if (d == 0) return Filt<0, 0>::v;
        if (d == 1) return Filt<0, 1>::v;
        return Filt<0, 2>::v;
    } else if (s == 1) {
        if (d == 0) return Filt<1, 0>::v;
        if (d == 1) return Filt<1, 1>::v;
        if (d == 2) return Filt<1, 2>::v;
        if (d == 3) return Filt<1, 3>::v;
        return Filt<1, 4>::v;
    } else {
        if (d == 0) return Filt<2, 0>::v;
        if (d == 1) return Filt<2, 1>::v;
        if (d == 2) return Filt<2, 2>::v;
        if (d == 3) return Filt<2, 3>::v;
        if (d == 4) return Filt<2, 4>::v;
        if (d == 5) return Filt<2, 5>::v;
        if (d == 6) return Filt<2, 6>::v;
        if (d == 7) return Filt<2, 7>::v;
        return Filt<2, 8>::v;
    }
}

// Packed mirror-pair tables (algebra verified rounds 3-6):
// point-antisymmetry G(-u,-v) = -G(u,v); x-mirror G_{nd-d}(u,v) = G_d(u,-v).
// out_d = P + Q, out_{nd-d} = P - Q;
//   A(j,k) = (G_dP(u,v)+G_dP(u,-v))/2, dP = (k==0 ? NH : k)
//   B(j,k) = (G_dQ(u,v)-G_dQ(u,-v))/2, dQ = (k==0 ? 0  : k)
// positions j: 0..6 (0,v) [A==0], 7..13 (u,0) [B==0], 14..62 (u,v) u,v>=1.
template <int NH> struct PTab { float a[63 * NH]; float b[63 * NH]; };

template <int NH>
constexpr PTab<NH> make_ptab(int s) {
    PTab<NH> t{};
    for (int j = 0; j < 63; ++j) {
        int u, v;
        if (j < 7)       { u = 0;     v = j + 1; }
        else if (j < 14) { u = j - 6; v = 0;     }
        else { int p = j - 14; u = p / 7 + 1; v = p % 7 + 1; }
        for (int k = 0; k < NH; ++k) {
            int dP = (k == 0) ? NH : k;
            int dQ = (k == 0) ? 0 : k;
            const F225& FP = getF(s, dP);
            const F225& FQ = getF(s, dQ);
            double A = 0.5 * (FP.v[(7 + u) * 15 + (7 + v)] + FP.v[(7 + u) * 15 + (7 - v)]);
            double B = 0.5 * (FQ.v[(7 + u) * 15 + (7 + v)] - FQ.v[(7 + u) * 15 + (7 - v)]);
            t.a[j * NH + k] = (float)A;
            t.b[j * NH + k] = (float)B;
        }
    }
    return t;
}
template <int S, int NH>
struct PTbl { static constexpr PTab<NH> t = make_ptab<NH>(S); };

// ============== directional bank: per-u template step (R=1) =================
// Compile-time U => every coefficient folds to an inline fp32 literal.
// Memory-clobber asm fences bound the scheduling window to one u-step
// (round-5 lesson: an unfenced straight-line body spills catastrophically).
// sm: flat LDS band tile, stride 48, 46 rows.
template <int SIDX, int NH, int U>
struct UStep {
    static __device__ __forceinline__ void run(
        const float* sm, int yb, int xc, float (&accP)[NH], float (&accQ)[NH]) {
        // Hc: v=0 (j=6+U): B==0, P only
        {
            float dvc = sm[(yb + U) * 48 + xc] - sm[(yb - U) * 48 + xc];
#pragma unroll
            for (int k = 0; k < NH; ++k)
                accP[k] = fmaf(PTbl<SIDX, NH>::t.a[(6 + U) * NH + k], dvc, accP[k]);
        }
        // Hp: v=1..7 (j=14+(U-1)*7+(v-1)): S->P, D->Q
#pragma unroll
        for (int v = 1; v <= 7; ++v) {
            float a_ = sm[(yb + U) * 48 + xc + v];
            float b_ = sm[(yb + U) * 48 + xc - v];
            float c_ = sm[(yb - U) * 48 + xc + v];
            float d_ = sm[(yb - U) * 48 + xc - v];
            float t1 = a_ - d_, t2 = b_ - c_;
            float S = t1 + t2, D = t1 - t2;
#pragma unroll
            for (int k = 0; k < NH; ++k) {
                accP[k] = fmaf(PTbl<SIDX, NH>::t.a[(14 + (U - 1) * 7 + (v - 1)) * NH + k], S, accP[k]);
                accQ[k] = fmaf(PTbl<SIDX, NH>::t.b[(14 + (U - 1) * 7 + (v - 1)) * NH + k], D, accQ[k]);
            }
        }
        asm volatile("" ::: "memory");  // scheduling fence between u-steps
        UStep<SIDX, NH, U + 1>::run(sm, yb, xc, accP, accQ);
    }
};
template <int SIDX, int NH>
struct UStep<SIDX, NH, 8> {
    static __device__ __forceinline__ void run(
        const float*, int, int, float (&)[NH], float (&)[NH]) {}
};

// One band's directional bank over a 32x32 tile; each thread loops 4 rows
// (R=1: with literal coefs, rows-per-thread amortizes nothing — R only
// inflates code size and acc VGPRs).
template <int SIDX, int NH>
__device__ __forceinline__ void dir_band(
    const float* sm, float* __restrict__ out, long nbase,
    int by, int bx, int tx, int ty, int c0) {
#pragma unroll 1
    for (int rr = 0; rr < 4; ++rr) {
        int yb = ty + 8 * rr + 7, xc = tx + 7;
        float accP[NH], accQ[NH];
#pragma unroll
        for (int k = 0; k < NH; ++k) { accP[k] = 0.f; accQ[k] = 0.f; }

        // H0: u=0, v=1..7 (j=v-1): A==0, Q only
#pragma unroll
        for (int v = 1; v <= 7; ++v) {
            float dv = sm[yb * 48 + xc + v] - sm[yb * 48 + xc - v];
#pragma unroll
            for (int k = 0; k < NH; ++k)
                accQ[k] = fmaf(PTbl<SIDX, NH>::t.b[(v - 1) * NH + k], dv, accQ[k]);
        }
        asm volatile("" ::: "memory");

        UStep<SIDX, NH, 1>::run(sm, yb, xc, accP, accQ);

        // d=0 -> Q[0]; d=NH -> P[0]; pair k: d=k -> P+Q, d=2NH-k -> P-Q
        long idx = nbase + (long)c0 * HWSZ + (long)(by + ty + 8 * rr) * WW + bx + tx;
        out[idx] = accQ[0];
        out[idx + (long)NH * HWSZ] = accP[0];
#pragma unroll
        for (int k = 1; k < NH; ++k) {
            out[idx + (long)k * HWSZ] = accP[k] + accQ[k];
            out[idx + (long)(2 * NH - k) * HWSZ] = accP[k] - accQ[k];
        }
    }
}

// ===================== fully-fused NSST kernel ==============================
// Per 32x32 tile: stage x with halo 13 (reflect) -> lp chain entirely in LDS
// -> band0/band1/band2 materialized in LDS -> three dir banks, zero
// intermediate HBM traffic. Buffer recycling (band order 0,1,2):
//   Xb: x[58][60]            -> lp1[50][52]
//   Tb: h0[58][56] -> band0 -> h1[54][52] -> band1 -> h2[50][48] -> band2
//   Pb: lp0[54][56]          -> lp2[46][48]
// Total LDS = 39,008 B -> 4 blocks/CU.
__global__ __launch_bounds__(256, 4) void nsst_fused(
    const float* __restrict__ x, float* __restrict__ out) {
    __shared__ float Xb[58 * 60];
    __shared__ float Tb[58 * 56];
    __shared__ float Pb[54 * 56];

    int n = blockIdx.z;
    int bx = blockIdx.x * 32, by = blockIdx.y * 32;
    int tx = threadIdx.x, ty = threadIdx.y;
    int tid = ty * 32 + tx;
    const float* ip = x + (long)n * HWSZ;
    long nbase = (long)n * 29 * HWSZ;

    // stage x[-13..44]^2 (58x58), reflect at input indexing
    for (int l = tid; l < 58 * 58; l += 256) {
        int r = l / 58, c = l % 58;
        Xb[r * 60 + c] = ip[(long)refl(by + r - 13, HH) * WW + refl(bx + c - 13, WW)];
    }
    __syncthreads();
    // h0 = H(x): rows[-13..44](58) x cols[-11..42](54), Tb stride 56
    for (int l = tid; l < 58 * 54; l += 256) {
        int r = l / 54, c = l % 54;
        float s = 0.f;
#pragma unroll
        for (int i = 0; i < 5; ++i) s = fmaf(LPW[i], Xb[r * 60 + c + i], s);
        Tb[r * 56 + c] = s;
    }
    __syncthreads();
    // lp0 = V(h0): [-11..42]^2 (54x54), Pb stride 56
    for (int l = tid; l < 54 * 54; l += 256) {
        int r = l / 54, c = l % 54;
        float s = 0.f;
#pragma unroll
        for (int i = 0; i < 5; ++i) s = fmaf(LPW[i], Tb[(r + i) * 56 + c], s);
        Pb[r * 56 + c] = s;
    }
    __syncthreads();
    // band0 = x - lp0 on [-7..38]^2 (46x46), Tb stride 48
    for (int l = tid; l < 46 * 46; l += 256) {
        int r = l / 46, c = l % 46;
        Tb[r * 48 + c] = Xb[(r + 6) * 60 + c + 6] - Pb[(r + 4) * 56 + c + 4];
    }
    __syncthreads();
    dir_band<0, 2>(Tb, out, nbase, by, bx, tx, ty, 0);   // channels 0..3
    __syncthreads();
    // h1 = H(lp0): rows[-11..42](54) x cols[-9..40](50), Tb stride 52
    for (int l = tid; l < 54 * 50; l += 256) {
        int r = l / 50, c = l % 50;
        float s = 0.f;
#pragma unroll
        for (int i = 0; i < 5; ++i) s = fmaf(LPW[i], Pb[r * 56 + c + i], s);
        Tb[r * 52 + c] = s;
    }
    __syncthreads();
    // lp1 = V(h1): [-9..40]^2 (50x50), Xb stride 52 (x is dead)
    for (int l = tid; l < 50 * 50; l += 256) {
        int r = l / 50, c = l % 50;
        float s = 0.f;
#pragma unroll
        for (int i = 0; i < 5; ++i) s = fmaf(LPW[i], Tb[(r + i) * 52 + c], s);
        Xb[r * 52 + c] = s;
    }
    __syncthreads();
    // band1 = lp0 - lp1 on 46x46, Tb stride 48
    for (int l = tid; l < 46 * 46; l += 256) {
        int r = l / 46, c = l % 46;
        Tb[r * 48 + c] = Pb[(r + 4) * 56 + c + 4] - Xb[(r + 2) * 52 + c + 2];
    }
    __syncthreads();
    dir_band<1, 4>(Tb, out, nbase, by, bx, tx, ty, 4);   // channels 4..11
    __syncthreads();
    // h2 = H(lp1): rows[-9..40](50) x cols[-7..38](46), Tb stride 48
    for (int l = tid; l < 50 * 46; l += 256) {
        int r = l / 46, c = l % 46;
        float s = 0.f;
#pragma unroll
        for (int i = 0; i < 5; ++i) s = fmaf(LPW[i], Xb[r * 52 + c + i], s);
        Tb[r * 48 + c] = s;
    }
    __syncthreads();
    // lp2 = V(h2): [-7..38]^2 (46x46), Pb stride 48 (lp0 dead)
    for (int l = tid; l < 46 * 46; l += 256) {
        int r = l / 46, c = l % 46;
        float s = 0.f;
#pragma unroll
        for (int i = 0; i < 5; ++i) s = fmaf(LPW[i], Tb[(r + i) * 48 + c], s);
        Pb[r * 48 + c] = s;
    }
    __syncthreads();
    // channel 28 = lp2 center
#pragma unroll
    for (int rr = 0; rr < 4; ++rr)
        out[nbase + 28l * HWSZ + (long)(by + ty + 8 * rr) * WW + bx + tx] =
            Pb[(ty + 8 * rr + 7) * 48 + tx + 7];
    // band2 = lp1 - lp2 on 46x46, Tb stride 48
    for (int l = tid; l < 46 * 46; l += 256) {
        int r = l / 46, c = l % 46;
        Tb[r * 48 + c] = Xb[(r + 2) * 52 + c + 2] - Pb[r * 48 + c];
    }
    __syncthreads();
    dir_band<2, 8>(Tb, out, nbase, by, bx, tx, ty, 12);  // channels 12..27
}

extern "C" void kernel_launch(void* const* d_in, const int* in_sizes, int n_in,
                              void* d_out, int out_size, void* d_ws, size_t ws_size,
                              hipStream_t stream) {
    const float* x = (const float*)d_in[0];
    float* out = (float*)d_out;
    (void)d_ws; (void)ws_size;

    nsst_fused<<<dim3(12, 12, NIMG), dim3(32, 8), 0, stream>>>(x, out);
}

// Round 8
// 558.485 us; speedup vs baseline: 1.9087x; 1.0639x over previous
//
#include <hip/hip_runtime.h>

#define HH 384
#define WW 384
#define HWSZ (HH * WW)
#define NIMG 24

typedef float v2f __attribute__((ext_vector_type(2)));

__device__ __forceinline__ int refl(int i, int n) {
    if (i < 0) i = -i;
    if (i >= n) i = 2 * n - 2 - i;
    return i;
}

// 5-tap Gaussian (sigma=1, normalized) as constexpr -> inline literals
constexpr float LPW[5] = {
    0.054488684549642945f, 0.24420134200323332f, 0.40261994689424746f,
    0.24420134200323332f, 0.054488684549642945f
};

// ===================== compile-time filter generation =======================
// constexpr fp64 math (range-reduced Taylor / Newton); error ~1e-16 rel.
// Numerically validated rounds 5-7 (absmax identical to runtime fp64 gen).
constexpr double CPI = 3.141592653589793;  // == numpy.pi as double

constexpr double cexp(double x) {
    int k = 0; double t = x;
    while (t > 0.25 || t < -0.25) { t *= 0.5; ++k; }
    double sum = 1.0, term = 1.0;
    for (int n = 1; n <= 14; ++n) { term *= t / n; sum += term; }
    for (int i = 0; i < k; ++i) sum *= sum;
    return sum;
}
constexpr double ccos(double x) {   // x in [0, pi)
    double sgn = 1.0;
    if (x > CPI * 0.5) { x = CPI - x; sgn = -1.0; }
    double x2 = x * x, sum = 1.0, term = 1.0;
    for (int n = 1; n <= 12; ++n) { term *= -x2 / ((2.0 * n - 1) * (2.0 * n)); sum += term; }
    return sgn * sum;
}
constexpr double csin(double x) {   // x in [0, pi)
    if (x > CPI * 0.5) x = CPI - x;
    double x2 = x * x, sum = x, term = x;
    for (int n = 1; n <= 12; ++n) { term *= -x2 / ((2.0 * n) * (2.0 * n + 1)); sum += term; }
    return sum;
}
constexpr double csqrt(double x) {
    if (x <= 0.0) return 0.0;
    double y = x > 1.0 ? x : 1.0;
    for (int i = 0; i < 80; ++i) y = 0.5 * (y + x / y);
    return y;
}

struct F225 { double v[225]; };

constexpr F225 make_filter(int s, int d, int nd) {
    double angle = CPI * (double)d / (double)nd;
    double scale = (double)(s + 1);
    double sx = 2.0 * scale, sy = 0.5 * scale;
    double ca = ccos(angle), sa = csin(angle);
    F225 f{};
    double sum = 0.0;
    for (int r = 0; r < 15; ++r)
        for (int c = 0; c < 15; ++c) {
            double X = (double)(c - 7), Y = (double)(r - 7);
            double Xr = X * ca - Y * sa;
            double Yr = X * sa + Y * ca;
            double k = cexp(-0.5 * (Xr * Xr / (sx * sx) + Yr * Yr / (sy * sy))) * Xr / (sx * sx);
            f.v[r * 15 + c] = k; sum += k;
        }
    double mean = sum / 225.0;
    double ss = 0.0;
    for (int i = 0; i < 225; ++i) { f.v[i] -= mean; ss += f.v[i] * f.v[i]; }
    double n = csqrt(ss);
    if (n > 1e-6) for (int i = 0; i < 225; ++i) f.v[i] /= n;
    return f;
}

template <int S, int D>
struct Filt { static constexpr F225 v = make_filter(S, D, S == 0 ? 4 : (S == 1 ? 8 : 16)); };

constexpr const F225& getF(int s, int d) {
    if (s == 0) {
        if (d == 0) return Filt<0, 0>::v;
        if (d == 1) return Filt<0, 1>::v;
        return Filt<0, 2>::v;
    } else if (s == 1) {
        if (d == 0) return Filt<1, 0>::v;
        if (d == 1) return Filt<1, 1>::v;
        if (d == 2) return Filt<1, 2>::v;
        if (d == 3) return Filt<1, 3>::v;
        return Filt<1, 4>::v;
    } else {
        if (d == 0) return Filt<2, 0>::v;
        if (d == 1) return Filt<2, 1>::v;
        if (d == 2) return Filt<2, 2>::v;
        if (d == 3) return Filt<2, 3>::v;
        if (d == 4) return Filt<2, 4>::v;
        if (d == 5) return Filt<2, 5>::v;
        if (d == 6) return Filt<2, 6>::v;
        if (d == 7) return Filt<2, 7>::v;
        return Filt<2, 8>::v;
    }
}

// Packed mirror-pair tables (algebra verified rounds 3-7):
// point-antisymmetry G(-u,-v) = -G(u,v); x-mirror G_{nd-d}(u,v) = G_d(u,-v).
// out_d = P + Q, out_{nd-d} = P - Q;
//   A(j,k) = (G_dP(u,v)+G_dP(u,-v))/2, dP = (k==0 ? NH : k)
//   B(j,k) = (G_dQ(u,v)-G_dQ(u,-v))/2, dQ = (k==0 ? 0  : k)
// positions j: 0..6 (0,v) [A==0], 7..13 (u,0) [B==0], 14..62 (u,v) u,v>=1.
template <int NH> struct PTab { float a[63 * NH]; float b[63 * NH]; };

template <int NH>
constexpr PTab<NH> make_ptab(int s) {
    PTab<NH> t{};
    for (int j = 0; j < 63; ++j) {
        int u, v;
        if (j < 7)       { u = 0;     v = j + 1; }
        else if (j < 14) { u = j - 6; v = 0;     }
        else { int p = j - 14; u = p / 7 + 1; v = p % 7 + 1; }
        for (int k = 0; k < NH; ++k) {
            int dP = (k == 0) ? NH : k;
            int dQ = (k == 0) ? 0 : k;
            const F225& FP = getF(s, dP);
            const F225& FQ = getF(s, dQ);
            double A = 0.5 * (FP.v[(7 + u) * 15 + (7 + v)] + FP.v[(7 + u) * 15 + (7 - v)]);
            double B = 0.5 * (FQ.v[(7 + u) * 15 + (7 + v)] - FQ.v[(7 + u) * 15 + (7 - v)]);
            t.a[j * NH + k] = (float)A;
            t.b[j * NH + k] = (float)B;
        }
    }
    return t;
}
template <int S, int NH>
struct PTbl { static constexpr PTab<NH> t = make_ptab<NH>(S); };

// ===================== dir-bank building blocks =============================
// 2-px load: consecutive floats, 4B-aligned -> one ds_read2_b32.
__device__ __forceinline__ v2f ld2(const float* p) {
    v2f r; r.x = p[0]; r.y = p[1]; return r;
}

constexpr unsigned fb(float f) { return __builtin_bit_cast(unsigned, f); }

// Guaranteed single-issue FMA with inline literal coefficient:
// VOP2 v_fmac_f32 allows a 32-bit literal in src0 (ISA sec.3) — avoids any
// v_mov materialization the compiler might emit for VOP3 v_fma_f32.
template <unsigned B>
__device__ __forceinline__ void fmac(float& a, float s) {
    asm("v_fmac_f32 %0, %2, %1" : "+v"(a) : "v"(s), "n"(B));
}

// K-recursion: one position j feeding P (coef A) or Q (coef B), both pixels.
template <int SIDX, int NH, int J, int K = 0>
__device__ __forceinline__ void accA(float (&P0)[NH], float (&P1)[NH],
                                     float sx, float sy) {
    if constexpr (K < NH) {
        constexpr unsigned b = fb(PTbl<SIDX, NH>::t.a[J * NH + K]);
        fmac<b>(P0[K], sx);
        fmac<b>(P1[K], sy);
        accA<SIDX, NH, J, K + 1>(P0, P1, sx, sy);
    }
}
template <int SIDX, int NH, int J, int K = 0>
__device__ __forceinline__ void accB(float (&Q0)[NH], float (&Q1)[NH],
                                     float dx, float dy) {
    if constexpr (K < NH) {
        constexpr unsigned b = fb(PTbl<SIDX, NH>::t.b[J * NH + K]);
        fmac<b>(Q0[K], dx);
        fmac<b>(Q1[K], dy);
        accB<SIDX, NH, J, K + 1>(Q0, Q1, dx, dy);
    }
}

// H0: u=0, v=1..7 (j=v-1): A==0, Q only.
template <int SIDX, int NH, int V = 1>
__device__ __forceinline__ void runH0(const float* r0,
                                      float (&Q0)[NH], float (&Q1)[NH]) {
    if constexpr (V <= 7) {
        v2f dv = ld2(r0 + V) - ld2(r0 - V);
        accB<SIDX, NH, V - 1>(Q0, Q1, dv.x, dv.y);
        runH0<SIDX, NH, V + 1>(r0, Q0, Q1);
    }
}

// Hp: v=1..7 for one u: S->P, D->Q.
template <int SIDX, int NH, int U, int V = 1>
__device__ __forceinline__ void runV(const float* rp, const float* rm,
                                     float (&P0)[NH], float (&Q0)[NH],
                                     float (&P1)[NH], float (&Q1)[NH]) {
    if constexpr (V <= 7) {
        v2f a = ld2(rp + V);
        v2f b = ld2(rp - V);
        v2f c = ld2(rm + V);
        v2f d = ld2(rm - V);
        v2f t1 = a - d, t2 = b - c;
        v2f S = t1 + t2, D = t1 - t2;
        constexpr int J = 14 + (U - 1) * 7 + (V - 1);
        accA<SIDX, NH, J>(P0, P1, S.x, S.y);
        accB<SIDX, NH, J>(Q0, Q1, D.x, D.y);
        runV<SIDX, NH, U, V + 1>(rp, rm, P0, Q0, P1, Q1);
    }
}

// u = 1..7; memory-clobber fence between u-steps bounds the scheduling
// window (round-5 lesson: unfenced straight-line body spills to scratch).
template <int SIDX, int NH, int U = 1>
__device__ __forceinline__ void runU(const float* sm, int yb, int xc,
                                     float (&P0)[NH], float (&Q0)[NH],
                                     float (&P1)[NH], float (&Q1)[NH]) {
    if constexpr (U <= 7) {
        const float* rp = sm + (yb + U) * 49 + xc;
        const float* rm = sm + (yb - U) * 49 + xc;
        {   // Hc: v=0 (j=6+U): B==0, P only
            v2f dvc = ld2(rp) - ld2(rm);
            accA<SIDX, NH, 6 + U>(P0, P1, dvc.x, dvc.y);
        }
        runV<SIDX, NH, U>(rp, rm, P0, Q0, P1, Q1);
        asm volatile("" ::: "memory");
        runU<SIDX, NH, U + 1>(sm, yb, xc, P0, Q0, P1, Q1);
    }
}

// One band over a 32x32 tile. Each thread: 2 adjacent x-pixels, 2 row-iters.
// sm: flat LDS band tile, stride 49 (odd -> stride-2 lane pattern stays
// <=2-way on banks), 46 rows, halo 7.
template <int SIDX, int NH>
__device__ __forceinline__ void dir_band(
    const float* sm, float* __restrict__ out, long nbase,
    int by, int bx, int lane, int c0) {
    int xg = (lane & 15) * 2;   // 0,2,..,30
    int yr = lane >> 4;         // 0..15
    int xc = xg + 7;
#pragma unroll 1
    for (int rr = 0; rr < 2; ++rr) {
        int yb = yr + 16 * rr + 7;
        float P0[NH], Q0[NH], P1[NH], Q1[NH];
#pragma unroll
        for (int k = 0; k < NH; ++k) { P0[k] = 0.f; Q0[k] = 0.f; P1[k] = 0.f; Q1[k] = 0.f; }

        runH0<SIDX, NH>(sm + yb * 49 + xc, Q0, Q1);
        asm volatile("" ::: "memory");
        runU<SIDX, NH>(sm, yb, xc, P0, Q0, P1, Q1);

        // d=0 -> Q[0]; d=NH -> P[0]; pair k: d=k -> P+Q, d=2NH-k -> P-Q
        long idx = nbase + (long)c0 * HWSZ + (long)(by + yr + 16 * rr) * WW + bx + xg;
        out[idx] = Q0[0];
        out[idx + 1] = Q1[0];
        out[idx + (long)NH * HWSZ] = P0[0];
        out[idx + (long)NH * HWSZ + 1] = P1[0];
#pragma unroll
        for (int k = 1; k < NH; ++k) {
            out[idx + (long)k * HWSZ] = P0[k] + Q0[k];
            out[idx + (long)k * HWSZ + 1] = P1[k] + Q1[k];
            out[idx + (long)(2 * NH - k) * HWSZ] = P0[k] - Q0[k];
            out[idx + (long)(2 * NH - k) * HWSZ + 1] = P1[k] - Q1[k];
        }
    }
}

// ===================== fully-fused NSST kernel ==============================
// Per 32x32 tile: stage x with halo 13 (reflect) -> lp chain in LDS ->
// band0/1/2 materialized in LDS (stride 49) -> three dir banks. Zero
// intermediate HBM traffic. Buffer recycling:
//   Xb: x[58][60]            -> lp1[50][52]
//   Tb: h0[58][56] -> band0[46][49] -> h1[54][52] -> band1 -> h2[50][48] -> band2
//   Pb: lp0[54][56]          -> lp2[46][48]
__global__ __launch_bounds__(256, 4) void nsst_fused(
    const float* __restrict__ x, float* __restrict__ out) {
    __shared__ float Xb[58 * 60];
    __shared__ float Tb[58 * 56];
    __shared__ float Pb[54 * 56];

    int n = blockIdx.z;
    int bx = blockIdx.x * 32, by = blockIdx.y * 32;
    int tx = threadIdx.x, ty = threadIdx.y;
    int lane = ty * 32 + tx;
    const float* ip = x + (long)n * HWSZ;
    long nbase = (long)n * 29 * HWSZ;

    // stage x[-13..44]^2 (58x58), reflect at input indexing (2D strides: no div)
    for (int r = ty; r < 58; r += 8) {
        int gy = refl(by + r - 13, HH);
        for (int c = tx; c < 58; c += 32)
            Xb[r * 60 + c] = ip[(long)gy * WW + refl(bx + c - 13, WW)];
    }
    __syncthreads();
    // h0 = H(x): 58 rows x 54 cols, Tb stride 56
    for (int r = ty; r < 58; r += 8)
        for (int c = tx; c < 54; c += 32) {
            float s = 0.f;
#pragma unroll
            for (int i = 0; i < 5; ++i) s = fmaf(LPW[i], Xb[r * 60 + c + i], s);
            Tb[r * 56 + c] = s;
        }
    __syncthreads();
    // lp0 = V(h0): 54x54, Pb stride 56
    for (int r = ty; r < 54; r += 8)
        for (int c = tx; c < 54; c += 32) {
            float s = 0.f;
#pragma unroll
            for (int i = 0; i < 5; ++i) s = fmaf(LPW[i], Tb[(r + i) * 56 + c], s);
            Pb[r * 56 + c] = s;
        }
    __syncthreads();
    // band0 = x - lp0 on 46x46, Tb stride 49
    for (int r = ty; r < 46; r += 8)
        for (int c = tx; c < 46; c += 32)
            Tb[r * 49 + c] = Xb[(r + 6) * 60 + c + 6] - Pb[(r + 4) * 56 + c + 4];
    __syncthreads();
    dir_band<0, 2>(Tb, out, nbase, by, bx, lane, 0);    // channels 0..3
    __syncthreads();
    // h1 = H(lp0): 54 rows x 50 cols, Tb stride 52
    for (int r = ty; r < 54; r += 8)
        for (int c = tx; c < 50; c += 32) {
            float s = 0.f;
#pragma unroll
            for (int i = 0; i < 5; ++i) s = fmaf(LPW[i], Pb[r * 56 + c + i], s);
            Tb[r * 52 + c] = s;
        }
    __syncthreads();
    // lp1 = V(h1): 50x50, Xb stride 52 (x is dead)
    for (int r = ty; r < 50; r += 8)
        for (int c = tx; c < 50; c += 32) {
            float s = 0.f;
#pragma unroll
            for (int i = 0; i < 5; ++i) s = fmaf(LPW[i], Tb[(r + i) * 52 + c], s);
            Xb[r * 52 + c] = s;
        }
    __syncthreads();
    // band1 = lp0 - lp1 on 46x46, Tb stride 49
    for (int r = ty; r < 46; r += 8)
        for (int c = tx; c < 46; c += 32)
            Tb[r * 49 + c] = Pb[(r + 4) * 56 + c + 4] - Xb[(r + 2) * 52 + c + 2];
    __syncthreads();
    dir_band<1, 4>(Tb, out, nbase, by, bx, lane, 4);    // channels 4..11
    __syncthreads();
    // h2 = H(lp1): 50 rows x 46 cols, Tb stride 48
    for (int r = ty; r < 50; r += 8)
        for (int c = tx; c < 46; c += 32) {
            float s = 0.f;
#pragma unroll
            for (int i = 0; i < 5; ++i) s = fmaf(LPW[i], Xb[r * 52 + c + i], s);
            Tb[r * 48 + c] = s;
        }
    __syncthreads();
    // lp2 = V(h2): 46x46, Pb stride 48 (lp0 dead)
    for (int r = ty; r < 46; r += 8)
        for (int c = tx; c < 46; c += 32) {
            float s = 0.f;
#pragma unroll
            for (int i = 0; i < 5; ++i) s = fmaf(LPW[i], Tb[(r + i) * 48 + c], s);
            Pb[r * 48 + c] = s;
        }
    __syncthreads();
    // channel 28 = lp2 center
#pragma unroll
    for (int rr = 0; rr < 4; ++rr)
        out[nbase + 28l * HWSZ + (long)(by + ty + 8 * rr) * WW + bx + tx] =
            Pb[(ty + 8 * rr + 7) * 48 + tx + 7];
    // band2 = lp1 - lp2 on 46x46, Tb stride 49 (h2 dead)
    for (int r = ty; r < 46; r += 8)
        for (int c = tx; c < 46; c += 32)
            Tb[r * 49 + c] = Xb[(r + 2) * 52 + c + 2] - Pb[r * 48 + c];
    __syncthreads();
    dir_band<2, 8>(Tb, out, nbase, by, bx, lane, 12);   // channels 12..27
}

extern "C" void kernel_launch(void* const* d_in, const int* in_sizes, int n_in,
                              void* d_out, int out_size, void* d_ws, size_t ws_size,
                              hipStream_t stream) {
    const float* x = (const float*)d_in[0];
    float* out = (float*)d_out;
    (void)d_ws; (void)ws_size;

    nsst_fused<<<dim3(12, 12, NIMG), dim3(32, 8), 0, stream>>>(x, out);
}